// Round 1
// baseline (965.437 us; speedup 1.0000x reference)
//
#include <hip/hip_runtime.h>

static constexpr float NEG_SLOPE = 0.2f;

// ---------------- Layer-1 node transform: xl1 = x@W1, a_src/a_dst ----------
__global__ void k_node1(const float* __restrict__ x,
                        const float* __restrict__ w1,    // [3,32]
                        const float* __restrict__ atts,  // [2,16]
                        const float* __restrict__ attd,  // [2,16]
                        float* __restrict__ xl,          // [N,32]
                        float* __restrict__ as_,         // [N,2]
                        float* __restrict__ ad_,         // [N,2]
                        int n) {
  int i = blockIdx.x * blockDim.x + threadIdx.x;
  if (i >= n) return;
  float x0 = x[3*i], x1 = x[3*i+1], x2 = x[3*i+2];
  float v[32];
#pragma unroll
  for (int j = 0; j < 32; ++j)
    v[j] = fmaf(x0, w1[j], fmaf(x1, w1[32+j], x2 * w1[64+j]));
  float s0=0.f, s1=0.f, d0=0.f, d1=0.f;
#pragma unroll
  for (int k = 0; k < 16; ++k) {
    s0 = fmaf(v[k],    atts[k],    s0);
    d0 = fmaf(v[k],    attd[k],    d0);
    s1 = fmaf(v[16+k], atts[16+k], s1);
    d1 = fmaf(v[16+k], attd[16+k], d1);
  }
  float4* o = reinterpret_cast<float4*>(xl + (size_t)i*32);
#pragma unroll
  for (int q = 0; q < 8; ++q)
    o[q] = make_float4(v[4*q], v[4*q+1], v[4*q+2], v[4*q+3]);
  as_[2*i] = s0; as_[2*i+1] = s1;
  ad_[2*i] = d0; ad_[2*i+1] = d1;
}

// ---------------- Edge pass: accumulate num[dst] += xl[src]*exp(lrelu(.)),
//                  den[dst] += exp(lrelu(.)).  LPE lanes cooperate per edge.
template<int CTOT, int CPH, int LPE>
__global__ void k_edge(const int* __restrict__ esrc,
                       const int* __restrict__ edst,
                       const float* __restrict__ xl,   // [N,CTOT]
                       const float* __restrict__ as_,  // [N,2]
                       const float* __restrict__ ad_,  // [N,2]
                       float* __restrict__ num,        // [N,CTOT]
                       float* __restrict__ den,        // [N,2]
                       int E, int n) {
  int tid = blockIdx.x * blockDim.x + threadIdx.x;
  int c = tid & (LPE - 1);
  int slot = tid / LPE;
  int nslots = (gridDim.x * blockDim.x) / LPE;
  int total = E + n;
  for (int e = slot; e < total; e += nslots) {
    int s, d;
    if (e < E) { s = esrc[e]; d = edst[e]; }
    else       { s = d = e - E; }                 // self-loop
    if (c < CTOT) {
      int h = c / CPH;
      float a = as_[2*s + h] + ad_[2*d + h];
      a = (a >= 0.f) ? a : NEG_SLOPE * a;
      float ee = __expf(a);
      float xv = xl[(size_t)s*CTOT + c];
      atomicAdd(&num[(size_t)d*CTOT + c], xv * ee);
      if (c == 0 || c == CPH)                     // one lane per head
        atomicAdd(&den[2*d + h], ee);
    }
  }
}

// ---------------- Layer-1 finalize + ReLU + Layer-2 transform --------------
__global__ void k_node2(const float* __restrict__ num1,  // [N,32]
                        const float* __restrict__ den1,  // [N,2]
                        const float* __restrict__ b1,    // [32]
                        const float* __restrict__ w2,    // [32,14]
                        const float* __restrict__ atts,  // [2,7]
                        const float* __restrict__ attd,  // [2,7]
                        float* __restrict__ xl2,         // [N,14]
                        float* __restrict__ as2,         // [N,2]
                        float* __restrict__ ad2,         // [N,2]
                        int n) {
  int i = blockIdx.x * blockDim.x + threadIdx.x;
  if (i >= n) return;
  float dh0 = den1[2*i]   + 1e-16f;
  float dh1 = den1[2*i+1] + 1e-16f;
  const float4* nr = reinterpret_cast<const float4*>(num1 + (size_t)i*32);
  float hbuf[32];
#pragma unroll
  for (int q = 0; q < 8; ++q) {
    float4 v = nr[q];
    float dd = (q < 4) ? dh0 : dh1;
    float t;
    t = v.x/dd + b1[4*q];   hbuf[4*q]   = t > 0.f ? t : 0.f;
    t = v.y/dd + b1[4*q+1]; hbuf[4*q+1] = t > 0.f ? t : 0.f;
    t = v.z/dd + b1[4*q+2]; hbuf[4*q+2] = t > 0.f ? t : 0.f;
    t = v.w/dd + b1[4*q+3]; hbuf[4*q+3] = t > 0.f ? t : 0.f;
  }
  float o[14];
#pragma unroll
  for (int j = 0; j < 14; ++j) o[j] = 0.f;
#pragma unroll
  for (int ch = 0; ch < 32; ++ch) {
#pragma unroll
    for (int j = 0; j < 14; ++j)
      o[j] = fmaf(hbuf[ch], w2[14*ch + j], o[j]);
  }
  float s0=0.f, s1=0.f, d0=0.f, d1=0.f;
#pragma unroll
  for (int k = 0; k < 7; ++k) {
    s0 = fmaf(o[k],   atts[k],   s0);
    d0 = fmaf(o[k],   attd[k],   d0);
    s1 = fmaf(o[7+k], atts[7+k], s1);
    d1 = fmaf(o[7+k], attd[7+k], d1);
  }
  float* xo = xl2 + (size_t)i*14;
#pragma unroll
  for (int j = 0; j < 14; ++j) xo[j] = o[j];
  as2[2*i] = s0; as2[2*i+1] = s1;
  ad2[2*i] = d0; ad2[2*i+1] = d1;
}

// ---------------- Layer-2 finalize: head-mean + bias + log_softmax ---------
__global__ void k_final(const float* __restrict__ num2,  // [N,14]
                        const float* __restrict__ den2,  // [N,2]
                        const float* __restrict__ b2,    // [7]
                        float* __restrict__ out,         // [N,7]
                        int n) {
  int i = blockIdx.x * blockDim.x + threadIdx.x;
  if (i >= n) return;
  float d0 = den2[2*i]   + 1e-16f;
  float d1 = den2[2*i+1] + 1e-16f;
  const float* nr = num2 + (size_t)i*14;
  float v[7];
#pragma unroll
  for (int c = 0; c < 7; ++c)
    v[c] = 0.5f*(nr[c]/d0 + nr[7+c]/d1) + b2[c];
  float m = v[0];
#pragma unroll
  for (int c = 1; c < 7; ++c) m = fmaxf(m, v[c]);
  float s = 0.f;
#pragma unroll
  for (int c = 0; c < 7; ++c) s += __expf(v[c]-m);
  float ls = __logf(s);
#pragma unroll
  for (int c = 0; c < 7; ++c) out[(size_t)i*7+c] = v[c]-m-ls;
}

extern "C" void kernel_launch(void* const* d_in, const int* in_sizes, int n_in,
                              void* d_out, int out_size, void* d_ws, size_t ws_size,
                              hipStream_t stream) {
  const float* x    = (const float*)d_in[0];
  const int*   ei   = (const int*)  d_in[1];
  const float* w1   = (const float*)d_in[2];
  const float* as1w = (const float*)d_in[3];
  const float* ad1w = (const float*)d_in[4];
  const float* b1   = (const float*)d_in[5];
  const float* w2   = (const float*)d_in[6];
  const float* as2w = (const float*)d_in[7];
  const float* ad2w = (const float*)d_in[8];
  const float* b2   = (const float*)d_in[9];
  float* out = (float*)d_out;

  const int n = in_sizes[0] / 3;
  const int E = in_sizes[1] / 2;
  const int* esrc = ei;
  const int* edst = ei + E;

  const size_t N = (size_t)n;
  float* ws = (float*)d_ws;
  // layout (floats):
  float* xl1  = ws;            // 32N
  float* as1  = ws + 32*N;     //  2N
  float* ad1  = ws + 34*N;     //  2N
  float* xl2  = ws + 36*N;     // 14N
  float* as2  = ws + 50*N;     //  2N
  float* ad2  = ws + 52*N;     //  2N
  float* num1 = ws + 54*N;     // 32N  -- zeroed region starts here
  float* den1 = ws + 86*N;     //  2N
  float* num2 = ws + 88*N;     // 14N
  float* den2 = ws + 102*N;    //  2N  -- total 104N floats

  // zero accumulators (num1,den1,num2,den2 are contiguous: 50N floats)
  hipMemsetAsync(num1, 0, 50*N*sizeof(float), stream);

  const int nb = (n + 255) / 256;
  k_node1<<<nb, 256, 0, stream>>>(x, w1, as1w, ad1w, xl1, as1, ad1, n);
  k_edge<32,16,32><<<8192, 256, 0, stream>>>(esrc, edst, xl1, as1, ad1, num1, den1, E, n);
  k_node2<<<nb, 256, 0, stream>>>(num1, den1, b1, w2, as2w, ad2w, xl2, as2, ad2, n);
  k_edge<14, 7,16><<<8192, 256, 0, stream>>>(esrc, edst, xl2, as2, ad2, num2, den2, E, n);
  k_final<<<nb, 256, 0, stream>>>(num2, den2, b2, out, n);
}

// Round 2
// 764.215 us; speedup vs baseline: 1.2633x; 1.2633x over previous
//
#include <hip/hip_runtime.h>

static constexpr float NEG_SLOPE = 0.2f;

// ---------------- Layer-1 node transform: xl1 = x@W1, a_src/a_dst ----------
__global__ void k_node1(const float* __restrict__ x,
                        const float* __restrict__ w1,    // [3,32]
                        const float* __restrict__ atts,  // [2,16]
                        const float* __restrict__ attd,  // [2,16]
                        float* __restrict__ xl,          // [N,32]
                        float* __restrict__ as_,         // [N,2]
                        float* __restrict__ ad_,         // [N,2]
                        int n) {
  int i = blockIdx.x * blockDim.x + threadIdx.x;
  if (i >= n) return;
  float x0 = x[3*i], x1 = x[3*i+1], x2 = x[3*i+2];
  float v[32];
#pragma unroll
  for (int j = 0; j < 32; ++j)
    v[j] = fmaf(x0, w1[j], fmaf(x1, w1[32+j], x2 * w1[64+j]));
  float s0=0.f, s1=0.f, d0=0.f, d1=0.f;
#pragma unroll
  for (int k = 0; k < 16; ++k) {
    s0 = fmaf(v[k],    atts[k],    s0);
    d0 = fmaf(v[k],    attd[k],    d0);
    s1 = fmaf(v[16+k], atts[16+k], s1);
    d1 = fmaf(v[16+k], attd[16+k], d1);
  }
  float4* o = reinterpret_cast<float4*>(xl + (size_t)i*32);
#pragma unroll
  for (int q = 0; q < 8; ++q)
    o[q] = make_float4(v[4*q], v[4*q+1], v[4*q+2], v[4*q+3]);
  as_[2*i] = s0; as_[2*i+1] = s1;
  ad_[2*i] = d0; ad_[2*i+1] = d1;
}

// ---------------- CSR build ------------------------------------------------
__global__ void k_count(const int* __restrict__ edst, unsigned* __restrict__ deg, int E) {
  int e = blockIdx.x * blockDim.x + threadIdx.x;
  if (e < E) atomicAdd(&deg[edst[e]], 1u);
}

// per-block inclusive scan of deg -> incl, block totals -> bsum
__global__ void k_scan1(const unsigned* __restrict__ deg, unsigned* __restrict__ incl,
                        unsigned* __restrict__ bsum, int n) {
  __shared__ unsigned sm[256];
  int i = blockIdx.x * 256 + threadIdx.x;
  unsigned v = (i < n) ? deg[i] : 0u;
  sm[threadIdx.x] = v; __syncthreads();
  for (int off = 1; off < 256; off <<= 1) {
    unsigned t = (threadIdx.x >= (unsigned)off) ? sm[threadIdx.x - off] : 0u;
    __syncthreads();
    sm[threadIdx.x] += t;
    __syncthreads();
  }
  if (i < n) incl[i] = sm[threadIdx.x];
  if (threadIdx.x == 255) bsum[blockIdx.x] = sm[255];
}

// single-block exclusive scan of bsum (nb <= 512)
__global__ void k_scan2(unsigned* __restrict__ bsum, int nb) {
  __shared__ unsigned sm[512];
  unsigned v = (threadIdx.x < (unsigned)nb) ? bsum[threadIdx.x] : 0u;
  sm[threadIdx.x] = v; __syncthreads();
  for (int off = 1; off < 512; off <<= 1) {
    unsigned t = (threadIdx.x >= (unsigned)off) ? sm[threadIdx.x - off] : 0u;
    __syncthreads();
    sm[threadIdx.x] += t;
    __syncthreads();
  }
  if (threadIdx.x < (unsigned)nb) bsum[threadIdx.x] = sm[threadIdx.x] - v;  // exclusive
}

// rp[i] = exclusive start; cursor[i] = same (scatter bumps it to row end)
__global__ void k_scan3(const unsigned* __restrict__ deg, const unsigned* __restrict__ incl,
                        const unsigned* __restrict__ bsum,
                        unsigned* __restrict__ rp, unsigned* __restrict__ cursor, int n) {
  int i = blockIdx.x * 256 + threadIdx.x;
  if (i >= n) return;
  unsigned excl = incl[i] - deg[i] + bsum[blockIdx.x];
  rp[i] = excl;
  cursor[i] = excl;
}

__global__ void k_scatter(const int* __restrict__ esrc, const int* __restrict__ edst,
                          unsigned* __restrict__ cursor, int* __restrict__ col, int E) {
  int e = blockIdx.x * blockDim.x + threadIdx.x;
  if (e >= E) return;
  int d = edst[e];
  unsigned slot = atomicAdd(&cursor[d], 1u);
  col[slot] = esrc[e];
}

// ---------------- Gather edge pass: LPE lanes per dst node -----------------
// num[d,c] = xl[d,c]*e_self + sum_{s in nbrs(d)} xl[s,c]*e(s,d);  den likewise.
template<int CTOT, int CPH, int LPE>
__global__ void k_gather(const unsigned* __restrict__ rp, const unsigned* __restrict__ rend,
                         const int* __restrict__ col,
                         const float* __restrict__ xl,   // [N,CTOT]
                         const float* __restrict__ as_,  // [N,2]
                         const float* __restrict__ ad_,  // [N,2]
                         float* __restrict__ num,        // [N,CTOT]
                         float* __restrict__ den,        // [N,2]
                         int n) {
  int d = blockIdx.x * (blockDim.x / LPE) + threadIdx.x / LPE;
  int c = threadIdx.x & (LPE - 1);
  if (d >= n) return;
  int h = (c < CTOT) ? c / CPH : 0;
  float adh = ad_[2*d + h];
  // self-loop term
  float a = as_[2*d + h] + adh;
  a = (a >= 0.f) ? a : NEG_SLOPE * a;
  float ee = __expf(a);
  float acc = (c < CTOT) ? xl[(size_t)d*CTOT + c] * ee : 0.f;
  float dsum = ee;
  unsigned jb = rp[d], je = rend[d];
  for (unsigned j = jb; j < je; ++j) {
    int s = col[j];
    a = as_[2*s + h] + adh;
    a = (a >= 0.f) ? a : NEG_SLOPE * a;
    ee = __expf(a);
    if (c < CTOT) acc = fmaf(xl[(size_t)s*CTOT + c], ee, acc);
    dsum += ee;
  }
  if (c < CTOT) num[(size_t)d*CTOT + c] = acc;
  if (c == 0)    den[2*d]     = dsum;
  if (c == CPH)  den[2*d + 1] = dsum;
}

// ---------------- Layer-1 finalize + ReLU + Layer-2 transform --------------
__global__ void k_node2(const float* __restrict__ num1,  // [N,32]
                        const float* __restrict__ den1,  // [N,2]
                        const float* __restrict__ b1,    // [32]
                        const float* __restrict__ w2,    // [32,14]
                        const float* __restrict__ atts,  // [2,7]
                        const float* __restrict__ attd,  // [2,7]
                        float* __restrict__ xl2,         // [N,14]
                        float* __restrict__ as2,         // [N,2]
                        float* __restrict__ ad2,         // [N,2]
                        int n) {
  int i = blockIdx.x * blockDim.x + threadIdx.x;
  if (i >= n) return;
  float dh0 = den1[2*i]   + 1e-16f;
  float dh1 = den1[2*i+1] + 1e-16f;
  const float4* nr = reinterpret_cast<const float4*>(num1 + (size_t)i*32);
  float hbuf[32];
#pragma unroll
  for (int q = 0; q < 8; ++q) {
    float4 v = nr[q];
    float dd = (q < 4) ? dh0 : dh1;
    float t;
    t = v.x/dd + b1[4*q];   hbuf[4*q]   = t > 0.f ? t : 0.f;
    t = v.y/dd + b1[4*q+1]; hbuf[4*q+1] = t > 0.f ? t : 0.f;
    t = v.z/dd + b1[4*q+2]; hbuf[4*q+2] = t > 0.f ? t : 0.f;
    t = v.w/dd + b1[4*q+3]; hbuf[4*q+3] = t > 0.f ? t : 0.f;
  }
  float o[14];
#pragma unroll
  for (int j = 0; j < 14; ++j) o[j] = 0.f;
#pragma unroll
  for (int ch = 0; ch < 32; ++ch) {
#pragma unroll
    for (int j = 0; j < 14; ++j)
      o[j] = fmaf(hbuf[ch], w2[14*ch + j], o[j]);
  }
  float s0=0.f, s1=0.f, d0=0.f, d1=0.f;
#pragma unroll
  for (int k = 0; k < 7; ++k) {
    s0 = fmaf(o[k],   atts[k],   s0);
    d0 = fmaf(o[k],   attd[k],   d0);
    s1 = fmaf(o[7+k], atts[7+k], s1);
    d1 = fmaf(o[7+k], attd[7+k], d1);
  }
  float* xo = xl2 + (size_t)i*14;
#pragma unroll
  for (int j = 0; j < 14; ++j) xo[j] = o[j];
  as2[2*i] = s0; as2[2*i+1] = s1;
  ad2[2*i] = d0; ad2[2*i+1] = d1;
}

// ---------------- Layer-2 finalize: head-mean + bias + log_softmax ---------
__global__ void k_final(const float* __restrict__ num2,  // [N,14]
                        const float* __restrict__ den2,  // [N,2]
                        const float* __restrict__ b2,    // [7]
                        float* __restrict__ out,         // [N,7]
                        int n) {
  int i = blockIdx.x * blockDim.x + threadIdx.x;
  if (i >= n) return;
  float d0 = den2[2*i]   + 1e-16f;
  float d1 = den2[2*i+1] + 1e-16f;
  const float* nr = num2 + (size_t)i*14;
  float v[7];
#pragma unroll
  for (int c = 0; c < 7; ++c)
    v[c] = 0.5f*(nr[c]/d0 + nr[7+c]/d1) + b2[c];
  float m = v[0];
#pragma unroll
  for (int c = 1; c < 7; ++c) m = fmaxf(m, v[c]);
  float s = 0.f;
#pragma unroll
  for (int c = 0; c < 7; ++c) s += __expf(v[c]-m);
  float ls = __logf(s);
#pragma unroll
  for (int c = 0; c < 7; ++c) out[(size_t)i*7+c] = v[c]-m-ls;
}

extern "C" void kernel_launch(void* const* d_in, const int* in_sizes, int n_in,
                              void* d_out, int out_size, void* d_ws, size_t ws_size,
                              hipStream_t stream) {
  const float* x    = (const float*)d_in[0];
  const int*   ei   = (const int*)  d_in[1];
  const float* w1   = (const float*)d_in[2];
  const float* as1w = (const float*)d_in[3];
  const float* ad1w = (const float*)d_in[4];
  const float* b1   = (const float*)d_in[5];
  const float* w2   = (const float*)d_in[6];
  const float* as2w = (const float*)d_in[7];
  const float* ad2w = (const float*)d_in[8];
  const float* b2   = (const float*)d_in[9];
  float* out = (float*)d_out;

  const int n = in_sizes[0] / 3;
  const int E = in_sizes[1] / 2;
  const int* esrc = ei;
  const int* edst = ei + E;

  const size_t N = (size_t)n;
  float* ws = (float*)d_ws;
  // layout in 4-byte units:
  float*    xl1    = ws;             // 32N
  float*    as1    = ws + 32*N;      //  2N
  float*    ad1    = ws + 34*N;      //  2N
  float*    xl2    = ws + 36*N;      // 14N
  float*    as2    = ws + 50*N;      //  2N
  float*    ad2    = ws + 52*N;      //  2N
  float*    num1   = ws + 54*N;      // 32N
  float*    den1   = ws + 86*N;      //  2N
  float*    num2   = ws + 88*N;      // 14N
  float*    den2   = ws + 102*N;     //  2N
  unsigned* deg    = (unsigned*)(ws + 104*N);  // N
  unsigned* incl   = (unsigned*)(ws + 105*N);  // N
  unsigned* rp     = (unsigned*)(ws + 106*N);  // N
  unsigned* cursor = (unsigned*)(ws + 107*N);  // N
  unsigned* bsum   = (unsigned*)(ws + 108*N);  // 1024
  int*      col    = (int*)(ws + 108*N + 1024); // E

  const int nbN = (n + 255) / 256;   // node-sized grids (also scan1/scan3 grid)
  const int nbE = (E + 255) / 256;   // edge-sized grids

  // zero only deg; everything else is written before being read
  hipMemsetAsync(deg, 0, N * sizeof(unsigned), stream);

  k_node1<<<nbN, 256, 0, stream>>>(x, w1, as1w, ad1w, xl1, as1, ad1, n);

  // CSR build (shared by both layers)
  k_count  <<<nbE, 256, 0, stream>>>(edst, deg, E);
  k_scan1  <<<nbN, 256, 0, stream>>>(deg, incl, bsum, n);
  k_scan2  <<<1, 512, 0, stream>>>(bsum, nbN);
  k_scan3  <<<nbN, 256, 0, stream>>>(deg, incl, bsum, rp, cursor, n);
  k_scatter<<<nbE, 256, 0, stream>>>(esrc, edst, cursor, col, E);
  // after k_scatter: cursor[d] == row end

  // Layer 1 edge pass (gather, no atomics): 32 lanes per node
  k_gather<32,16,32><<<(n*32 + 255)/256, 256, 0, stream>>>(rp, cursor, col, xl1, as1, ad1, num1, den1, n);
  k_node2<<<nbN, 256, 0, stream>>>(num1, den1, b1, w2, as2w, ad2w, xl2, as2, ad2, n);

  // Layer 2 edge pass: 16 lanes per node (14 active channels)
  k_gather<14,7,16><<<(n*16 + 255)/256, 256, 0, stream>>>(rp, cursor, col, xl2, as2, ad2, num2, den2, n);
  k_final<<<nbN, 256, 0, stream>>>(num2, den2, b2, out, n);
}